// Round 1
// baseline (3894.805 us; speedup 1.0000x reference)
//
#include <hip/hip_runtime.h>
#include <math.h>

// Problem constants (reference: B,P,NTIME,NLATENT,NSPATIAL = 4,2,16,32,2048)
#define NB 4
#define NP 2
#define NT 16
#define NC 32
#define NX 2048

// ---------------------------------------------------------------------------
// Precompute G[c,e,A,B] = sum_{t,T} enc[e,t,T] * K[t,A,c] * V[T,B,c]
// For layer 1 (cstride==1) there is no c axis: G[e,A,B].
// One block per (c,e) pair; 256 threads.
// ---------------------------------------------------------------------------
__global__ void g_precompute(const float* __restrict__ K,
                             const float* __restrict__ V,
                             const float* __restrict__ enc,
                             float* __restrict__ G,
                             int cstride) {
    const int bid = blockIdx.x;
    int e, c;
    if (cstride == 1) { e = bid; c = 0; }
    else              { c = bid >> 4; e = bid & 15; }

    __shared__ float sK[256], sV[256], sE[256], sW[256];
    const int tid = threadIdx.x;
    {
        const int t = tid >> 4, A = tid & 15;
        sK[tid] = K[(t * 16 + A) * cstride + c];
        sV[tid] = V[(t * 16 + A) * cstride + c];
        sE[tid] = enc[(e * 16 + t) * 16 + A];
    }
    __syncthreads();
    // step 1: W[t,B] = sum_T enc[e,t,T] * V[T,B,c]
    {
        const int t = tid >> 4, Bi = tid & 15;
        float acc = 0.f;
#pragma unroll
        for (int T = 0; T < 16; ++T) acc += sE[t * 16 + T] * sV[T * 16 + Bi];
        sW[tid] = acc;
    }
    __syncthreads();
    // step 2: G[A,B] = sum_t K[t,A,c] * W[t,B]
    {
        const int A = tid >> 4, Bi = tid & 15;
        float acc = 0.f;
#pragma unroll
        for (int t = 0; t < 16; ++t) acc += sK[t * 16 + A] * sW[t * 16 + Bi];
        G[((c * 16 + e) * 16 + A) * 16 + Bi] = acc;
    }
}

__device__ __forceinline__ float sqrt_act(float v) {
    return copysignf(sqrtf(fabsf(v)), v);
}

// ---------------------------------------------------------------------------
// Main kernel: one thread per (b,p,c,x) site.
// grid = NB*NP*NC*(NX/256) = 2048 blocks of 256 threads.
// bid bits: [2:0]=x-chunk, [7:3]=c, [10:8]=bp
// ---------------------------------------------------------------------------
__global__ __launch_bounds__(256) void site_kernel(
    const float* __restrict__ x,
    const float* __restrict__ Q0,
    const float* __restrict__ Q1,
    const float* __restrict__ dec,
    const float* __restrict__ a,
    const float* __restrict__ w,
    const float* __restrict__ G0,
    const float* __restrict__ G1,
    float* __restrict__ out) {
    const int tid = threadIdx.x;
    const int bid = blockIdx.x;
    const int xc = bid & 7;
    const int c  = (bid >> 3) & 31;
    const int bp = bid >> 8;             // [0, NB*NP)
    const int xx = (xc << 8) + tid;      // [0, NX)

    // ---- load the 16-vector over time (coalesced across lanes) ----
    float Xv[16];
    const float* xbase = x + (bp * NT * NC + c) * NX + xx;
#pragma unroll
    for (int t = 0; t < 16; ++t) Xv[t] = xbase[t * NC * NX];

    // ---- q0[t] = sum_T Q0[t,T,c] * Xv[T] ----
    float q0[16];
#pragma unroll
    for (int t = 0; t < 16; ++t) {
        float acc = 0.f;
#pragma unroll
        for (int T = 0; T < 16; ++T) acc += Q0[(t * 16 + T) * NC + c] * Xv[T];
        q0[t] = acc;
    }

    // ---- h[e] = sqrt_act( Xv^T G0[c,e] Xv ) ----
    float h[16];
    const float* G0c = G0 + c * 4096;
#pragma unroll
    for (int e = 0; e < 16; ++e) {
        float acc = 0.f;
#pragma unroll
        for (int A = 0; A < 16; ++A) {
            float s = 0.f;
#pragma unroll
            for (int Bq = 0; Bq < 16; ++Bq)
                s += G0c[(e * 16 + A) * 16 + Bq] * Xv[Bq];
            acc += Xv[A] * s;
        }
        h[e] = sqrt_act(acc);
    }

    // ---- q1[t] = sum_T Q1[t,T] * h[T] ----
    float q1[16];
#pragma unroll
    for (int t = 0; t < 16; ++t) {
        float acc = 0.f;
#pragma unroll
        for (int T = 0; T < 16; ++T) acc += Q1[t * 16 + T] * h[T];
        q1[t] = acc;
    }

    // ---- h2[e] = sqrt_act( h^T G1[e] h );  b1[e] = a[e,x]*h2[e] ----
    float b1[16];
#pragma unroll
    for (int e = 0; e < 16; ++e) {
        float acc = 0.f;
#pragma unroll
        for (int A = 0; A < 16; ++A) {
            float s = 0.f;
#pragma unroll
            for (int Bq = 0; Bq < 16; ++Bq)
                s += G1[(e * 16 + A) * 16 + Bq] * h[Bq];
            acc += h[A] * s;
        }
        b1[e] = a[e * NX + xx] * sqrt_act(acc);
    }

    // ---- b2[E] = sum_{t,e} q1[t] * b1[e] * dec[e,t,E] ----
    float b2[16];
#pragma unroll
    for (int E = 0; E < 16; ++E) {
        float acc = 0.f;
#pragma unroll
        for (int t = 0; t < 16; ++t) {
            float s = 0.f;
#pragma unroll
            for (int e = 0; e < 16; ++e)
                s += dec[(e * 16 + t) * 16 + E] * b1[e];
            acc += q1[t] * s;
        }
        b2[E] = acc;
    }

    // ---- b3[T] = sum_{t,E} q0[t] * b2[E] * dec[E,t,T];  y += w[T,x]*b3[T] ----
    float y = 0.f;
#pragma unroll
    for (int T = 0; T < 16; ++T) {
        float acc = 0.f;
#pragma unroll
        for (int t = 0; t < 16; ++t) {
            float s = 0.f;
#pragma unroll
            for (int E = 0; E < 16; ++E)
                s += dec[(E * 16 + t) * 16 + T] * b2[E];
            acc += q0[t] * s;
        }
        y += w[T * NX + xx] * acc;
    }

    // ---- reduce over the block, atomicAdd once per block ----
#pragma unroll
    for (int off = 32; off > 0; off >>= 1) y += __shfl_down(y, off);
    __shared__ float red[4];
    if ((tid & 63) == 0) red[tid >> 6] = y;
    __syncthreads();
    if (tid == 0) {
        atomicAdd(&out[bp * NC + c], red[0] + red[1] + red[2] + red[3]);
    }
}

extern "C" void kernel_launch(void* const* d_in, const int* in_sizes, int n_in,
                              void* d_out, int out_size, void* d_ws, size_t ws_size,
                              hipStream_t stream) {
    const float* x   = (const float*)d_in[0];
    const float* K0  = (const float*)d_in[1];
    const float* Q0  = (const float*)d_in[2];
    const float* V0  = (const float*)d_in[3];
    const float* K1  = (const float*)d_in[4];
    const float* Q1  = (const float*)d_in[5];
    const float* V1  = (const float*)d_in[6];
    const float* enc = (const float*)d_in[7];
    const float* dec = (const float*)d_in[8];
    const float* a   = (const float*)d_in[9];
    const float* w   = (const float*)d_in[10];
    float* out = (float*)d_out;

    float* G0 = (float*)d_ws;              // NC*16*16*16 = 131072 floats
    float* G1 = G0 + NC * 16 * 16 * 16;    // 16*16*16    = 4096 floats

    // out must be zeroed every call (harness re-poisons with 0xAA)
    hipMemsetAsync(d_out, 0, (size_t)out_size * sizeof(float), stream);

    g_precompute<<<NC * 16, 256, 0, stream>>>(K0, V0, enc, G0, NC);
    g_precompute<<<16,      256, 0, stream>>>(K1, V1, enc, G1, 1);

    const int nblocks = NB * NP * NC * (NX / 256);  // 2048
    site_kernel<<<nblocks, 256, 0, stream>>>(x, Q0, Q1, dec, a, w, G0, G1, out);
}

// Round 2
// 680.883 us; speedup vs baseline: 5.7202x; 5.7202x over previous
//
#include <hip/hip_runtime.h>
#include <math.h>

// Problem constants (reference: B,P,NTIME,NLATENT,NSPATIAL = 4,2,16,32,2048)
#define NB 4
#define NP 2
#define NT 16
#define NC 32
#define NX 2048

// ---------------------------------------------------------------------------
// Precompute G[c,e,A,B] = sum_{t,T} enc[e,t,T] * K[t,A,c] * V[T,B,c]
// For layer 1 (cstride==1) there is no c axis: G[e,A,B].
// One block per (c,e) pair; 256 threads.
// ---------------------------------------------------------------------------
__global__ void g_precompute(const float* __restrict__ K,
                             const float* __restrict__ V,
                             const float* __restrict__ enc,
                             float* __restrict__ G,
                             int cstride) {
    const int bid = blockIdx.x;
    int e, c;
    if (cstride == 1) { e = bid; c = 0; }
    else              { c = bid >> 4; e = bid & 15; }

    __shared__ float sK[256], sV[256], sE[256], sW[256];
    const int tid = threadIdx.x;
    {
        const int t = tid >> 4, A = tid & 15;
        sK[tid] = K[(t * 16 + A) * cstride + c];
        sV[tid] = V[(t * 16 + A) * cstride + c];
        sE[tid] = enc[(e * 16 + t) * 16 + A];
    }
    __syncthreads();
    // step 1: W[t,B] = sum_T enc[e,t,T] * V[T,B,c]
    {
        const int t = tid >> 4, Bi = tid & 15;
        float acc = 0.f;
#pragma unroll
        for (int T = 0; T < 16; ++T) acc += sE[t * 16 + T] * sV[T * 16 + Bi];
        sW[tid] = acc;
    }
    __syncthreads();
    // step 2: G[A,B] = sum_t K[t,A,c] * W[t,B]
    {
        const int A = tid >> 4, Bi = tid & 15;
        float acc = 0.f;
#pragma unroll
        for (int t = 0; t < 16; ++t) acc += sK[t * 16 + A] * sW[t * 16 + Bi];
        G[((c * 16 + e) * 16 + A) * 16 + Bi] = acc;
    }
}

// ---------------------------------------------------------------------------
// Weight transposes so every inner reduction is a contiguous 16-dword row:
//   Q0t[c][t][T]  = Q0[t,T,c]
//   decT[t][E][e] = dec[e,t,E]   (for b2 stage, sum over e)
//   decT2[t][T][E]= dec[E,t,T]   (for final stage, sum over E)
// ---------------------------------------------------------------------------
__global__ void w_transpose(const float* __restrict__ Q0,
                            const float* __restrict__ dec,
                            float* __restrict__ Q0t,
                            float* __restrict__ decT,
                            float* __restrict__ decT2) {
    const int tid = blockIdx.x * 256 + threadIdx.x;  // 0..8191
    if (tid < 8192) {
        const int c = tid >> 8, t = (tid >> 4) & 15, T = tid & 15;
        Q0t[tid] = Q0[(t * 16 + T) * NC + c];
    }
    if (tid < 4096) {
        const int t = tid >> 8, j = (tid >> 4) & 15, i = tid & 15;
        // decT[t][E=j][e=i] = dec[e,t,E]
        decT[tid]  = dec[(i * 16 + t) * 16 + j];
        // decT2[t][T=j][E=i] = dec[E,t,T]
        decT2[tid] = dec[(i * 16 + t) * 16 + j] == 0.f ? dec[(i * 16 + t) * 16 + j] : dec[(i * 16 + t) * 16 + j]; // placeholder avoided below
    }
    // NOTE: decT2 needs a different permutation; recompute cleanly:
    if (tid < 4096) {
        const int t = tid >> 8, T = (tid >> 4) & 15, E = tid & 15;
        decT2[tid] = dec[(E * 16 + t) * 16 + T];
    }
}

__device__ __forceinline__ float sqrt_act(float v) {
    return copysignf(sqrtf(fabsf(v)), v);
}

// ---------------------------------------------------------------------------
// Main kernel: one thread per (b,p,c,x) site.
// Outer e/E/T loops are REAL loops (small code, I$-friendly); inner 16-dots
// are unrolled over registers. Loop-indexed stage outputs go through LDS
// used as a per-thread indexable array (no cross-thread sharing, no syncs).
// grid = NB*NP*NC*(NX/256) = 2048 blocks of 256 threads.
// ---------------------------------------------------------------------------
__global__ __launch_bounds__(256) void site_kernel(
    const float* __restrict__ x,
    const float* __restrict__ Q0t,
    const float* __restrict__ Q1,
    const float* __restrict__ decT,
    const float* __restrict__ decT2,
    const float* __restrict__ a,
    const float* __restrict__ w,
    const float* __restrict__ G0,
    const float* __restrict__ G1,
    float* __restrict__ out) {
    const int tid = threadIdx.x;
    const int bid = blockIdx.x;
    const int xc = bid & 7;
    const int c  = (bid >> 3) & 31;
    const int bp = bid >> 8;             // [0, NB*NP)
    const int xx = (xc << 8) + tid;      // [0, NX)

    __shared__ float lds[16][256];       // per-thread scratch column [i][tid]

    // ---- load the 16-vector over time (coalesced across lanes) ----
    float X[16];
    const float* xbase = x + (bp * NT * NC + c) * NX + xx;
#pragma unroll
    for (int t = 0; t < 16; ++t) X[t] = xbase[t * NC * NX];

    // ---- q0[t] = sum_T Q0t[c][t][T] * X[T]  (unrolled, stays in regs) ----
    float q0[16];
    {
        const float* Qc = Q0t + c * 256;
#pragma unroll
        for (int t = 0; t < 16; ++t) {
            float sa = 0.f, sb = 0.f;
#pragma unroll
            for (int T = 0; T < 16; T += 2) {
                sa += Qc[t * 16 + T] * X[T];
                sb += Qc[t * 16 + T + 1] * X[T + 1];
            }
            q0[t] = sa + sb;
        }
    }

    // ---- layer 0: h[e] = sqrt_act( X^T G0[c,e] X )  -> lds ----
    {
        const float* G0c = G0 + c * 4096;
#pragma unroll 1
        for (int e = 0; e < 16; ++e) {
            const float* g = G0c + e * 256;
            float acc0 = 0.f, acc1 = 0.f;
#pragma unroll
            for (int A = 0; A < 16; ++A) {
                float sa = 0.f, sb = 0.f;
#pragma unroll
                for (int B = 0; B < 16; B += 2) {
                    sa += g[A * 16 + B] * X[B];
                    sb += g[A * 16 + B + 1] * X[B + 1];
                }
                if (A & 1) acc1 += X[A] * (sa + sb);
                else       acc0 += X[A] * (sa + sb);
            }
            lds[e][tid] = sqrt_act(acc0 + acc1);
        }
    }

    // ---- h -> regs (X dead from here) ----
    float h[16];
#pragma unroll
    for (int e = 0; e < 16; ++e) h[e] = lds[e][tid];

    // ---- q1[t] = sum_T Q1[t,T] * h[T]  (unrolled, regs) ----
    float q1[16];
    {
#pragma unroll
        for (int t = 0; t < 16; ++t) {
            float sa = 0.f, sb = 0.f;
#pragma unroll
            for (int T = 0; T < 16; T += 2) {
                sa += Q1[t * 16 + T] * h[T];
                sb += Q1[t * 16 + T + 1] * h[T + 1];
            }
            q1[t] = sa + sb;
        }
    }

    // ---- layer 1: b1[e] = a[e,x] * sqrt_act( h^T G1[e] h ) -> lds ----
    {
#pragma unroll 1
        for (int e = 0; e < 16; ++e) {
            const float* g = G1 + e * 256;
            float acc0 = 0.f, acc1 = 0.f;
#pragma unroll
            for (int A = 0; A < 16; ++A) {
                float sa = 0.f, sb = 0.f;
#pragma unroll
                for (int B = 0; B < 16; B += 2) {
                    sa += g[A * 16 + B] * h[B];
                    sb += g[A * 16 + B + 1] * h[B + 1];
                }
                if (A & 1) acc1 += h[A] * (sa + sb);
                else       acc0 += h[A] * (sa + sb);
            }
            lds[e][tid] = a[e * NX + xx] * sqrt_act(acc0 + acc1);
        }
    }

    // ---- b1 -> regs (h dead after this stage's consumers) ----
    float b1[16];
#pragma unroll
    for (int e = 0; e < 16; ++e) b1[e] = lds[e][tid];

    // ---- b2[E] = sum_t q1[t] * ( sum_e decT[t][E][e] * b1[e] ) -> lds ----
    {
#pragma unroll 1
        for (int E = 0; E < 16; ++E) {
            float acc0 = 0.f, acc1 = 0.f;
#pragma unroll
            for (int t = 0; t < 16; ++t) {
                const float* d = decT + (t * 16 + E) * 16;
                float sa = 0.f, sb = 0.f;
#pragma unroll
                for (int e2 = 0; e2 < 16; e2 += 2) {
                    sa += d[e2] * b1[e2];
                    sb += d[e2 + 1] * b1[e2 + 1];
                }
                if (t & 1) acc1 += q1[t] * (sa + sb);
                else       acc0 += q1[t] * (sa + sb);
            }
            lds[E][tid] = acc0 + acc1;
        }
    }

    float b2[16];
#pragma unroll
    for (int E = 0; E < 16; ++E) b2[E] = lds[E][tid];

    // ---- y = sum_T w[T,x] * sum_t q0[t] * ( sum_E decT2[t][T][E] * b2[E] ) ----
    float y = 0.f;
    {
#pragma unroll 1
        for (int T = 0; T < 16; ++T) {
            float acc0 = 0.f, acc1 = 0.f;
#pragma unroll
            for (int t = 0; t < 16; ++t) {
                const float* d = decT2 + (t * 16 + T) * 16;
                float sa = 0.f, sb = 0.f;
#pragma unroll
                for (int E = 0; E < 16; E += 2) {
                    sa += d[E] * b2[E];
                    sb += d[E + 1] * b2[E + 1];
                }
                if (t & 1) acc1 += q0[t] * (sa + sb);
                else       acc0 += q0[t] * (sa + sb);
            }
            y += w[T * NX + xx] * (acc0 + acc1);
        }
    }

    // ---- reduce over the block, one atomic per block ----
#pragma unroll
    for (int off = 32; off > 0; off >>= 1) y += __shfl_down(y, off);
    __shared__ float red[4];
    if ((tid & 63) == 0) red[tid >> 6] = y;
    __syncthreads();
    if (tid == 0) {
        atomicAdd(&out[bp * NC + c], red[0] + red[1] + red[2] + red[3]);
    }
}

extern "C" void kernel_launch(void* const* d_in, const int* in_sizes, int n_in,
                              void* d_out, int out_size, void* d_ws, size_t ws_size,
                              hipStream_t stream) {
    const float* x   = (const float*)d_in[0];
    const float* K0  = (const float*)d_in[1];
    const float* Q0  = (const float*)d_in[2];
    const float* V0  = (const float*)d_in[3];
    const float* K1  = (const float*)d_in[4];
    const float* Q1  = (const float*)d_in[5];
    const float* V1  = (const float*)d_in[6];
    const float* enc = (const float*)d_in[7];
    const float* dec = (const float*)d_in[8];
    const float* a   = (const float*)d_in[9];
    const float* w   = (const float*)d_in[10];
    float* out = (float*)d_out;

    float* G0    = (float*)d_ws;             // 32*16*16*16 = 131072 floats
    float* G1    = G0 + NC * 4096;           // 4096
    float* Q0t   = G1 + 4096;                // 8192
    float* decT  = Q0t + 8192;               // 4096
    float* decT2 = decT + 4096;              // 4096

    // out must be zeroed every call (harness re-poisons with 0xAA)
    hipMemsetAsync(d_out, 0, (size_t)out_size * sizeof(float), stream);

    g_precompute<<<NC * 16, 256, 0, stream>>>(K0, V0, enc, G0, NC);
    g_precompute<<<16,      256, 0, stream>>>(K1, V1, enc, G1, 1);
    w_transpose<<<32, 256, 0, stream>>>(Q0, dec, Q0t, decT, decT2);

    const int nblocks = NB * NP * NC * (NX / 256);  // 2048
    site_kernel<<<nblocks, 256, 0, stream>>>(x, Q0t, Q1, decT, decT2,
                                             a, w, G0, G1, out);
}

// Round 3
// 564.816 us; speedup vs baseline: 6.8957x; 1.2055x over previous
//
#include <hip/hip_runtime.h>
#include <math.h>

// Problem constants (reference: B,P,NTIME,NLATENT,NSPATIAL = 4,2,16,32,2048)
#define NB 4
#define NP 2
#define NT 16
#define NC 32
#define NX 2048

// ---------------------------------------------------------------------------
// Precompute G[c,e,A,B] = sum_{t,T} enc[e,t,T] * K[t,A,c] * V[T,B,c]
// For layer 1 (cstride==1) there is no c axis: G[e,A,B].
// ---------------------------------------------------------------------------
__global__ void g_precompute(const float* __restrict__ K,
                             const float* __restrict__ V,
                             const float* __restrict__ enc,
                             float* __restrict__ G,
                             int cstride) {
    const int bid = blockIdx.x;
    int e, c;
    if (cstride == 1) { e = bid; c = 0; }
    else              { c = bid >> 4; e = bid & 15; }

    __shared__ float sK[256], sV[256], sE[256], sW[256];
    const int tid = threadIdx.x;
    {
        const int t = tid >> 4, A = tid & 15;
        sK[tid] = K[(t * 16 + A) * cstride + c];
        sV[tid] = V[(t * 16 + A) * cstride + c];
        sE[tid] = enc[(e * 16 + t) * 16 + A];
    }
    __syncthreads();
    {   // W[t,B] = sum_T enc[e,t,T] * V[T,B,c]
        const int t = tid >> 4, Bi = tid & 15;
        float acc = 0.f;
#pragma unroll
        for (int T = 0; T < 16; ++T) acc += sE[t * 16 + T] * sV[T * 16 + Bi];
        sW[tid] = acc;
    }
    __syncthreads();
    {   // G[A,B] = sum_t K[t,A,c] * W[t,B]
        const int A = tid >> 4, Bi = tid & 15;
        float acc = 0.f;
#pragma unroll
        for (int t = 0; t < 16; ++t) acc += sK[t * 16 + A] * sW[t * 16 + Bi];
        G[((c * 16 + e) * 16 + A) * 16 + Bi] = acc;
    }
}

// M1[E][T][e] = sum_t Q1[t,T] * dec[e,t,E]   (fuses q1-projection into b2 stage)
__global__ void m1_precompute(const float* __restrict__ Q1,
                              const float* __restrict__ dec,
                              float* __restrict__ M1) {
    const int idx = blockIdx.x * 256 + threadIdx.x;  // 4096
    const int E = idx >> 8, T = (idx >> 4) & 15, e = idx & 15;
    float acc = 0.f;
#pragma unroll
    for (int t = 0; t < 16; ++t)
        acc += Q1[t * 16 + T] * dec[(e * 16 + t) * 16 + E];
    M1[idx] = acc;
}

// M2[c][T][A][E] = sum_t Q0[t,A,c] * dec[E,t,T]  (fuses q0-projection into final stage)
__global__ void m2_precompute(const float* __restrict__ Q0,
                              const float* __restrict__ dec,
                              float* __restrict__ M2) {
    const int idx = blockIdx.x * 256 + threadIdx.x;  // 131072
    const int c = idx >> 12, T = (idx >> 8) & 15, A = (idx >> 4) & 15, E = idx & 15;
    float acc = 0.f;
#pragma unroll
    for (int t = 0; t < 16; ++t)
        acc += Q0[(t * 16 + A) * NC + c] * dec[(E * 16 + t) * 16 + T];
    M2[idx] = acc;
}

__device__ __forceinline__ float sqrt_act(float v) {
    return copysignf(sqrtf(fabsf(v)), v);
}

// dot of one shared 16-float weight row against TWO per-thread 16-vectors.
// 4 independent FMA chains; weight row comes from wave-uniform address (s_load).
__device__ __forceinline__ void dot2(const float* __restrict__ row,
                                     const float (&v0)[16], const float (&v1)[16],
                                     float& s0, float& s1) {
    float a0 = 0.f, b0 = 0.f, a1 = 0.f, b1 = 0.f;
#pragma unroll
    for (int i = 0; i < 16; i += 2) {
        a0 += row[i] * v0[i];     b0 += row[i + 1] * v0[i + 1];
        a1 += row[i] * v1[i];     b1 += row[i + 1] * v1[i + 1];
    }
    s0 = a0 + b0;
    s1 = a1 + b1;
}

// ---------------------------------------------------------------------------
// Main kernel: one thread per TWO (b,p,c,x) sites (x and x+256).
// All intermediates live in registers; stage outputs never touch LDS.
// grid = NB*NP*NC*(NX/512) = 1024 blocks of 256 threads.
// bid bits: [1:0]=x-chunk, [6:2]=c, [9:7]=bp
// ---------------------------------------------------------------------------
__global__ __launch_bounds__(256) void site_kernel(
    const float* __restrict__ x,
    const float* __restrict__ a,
    const float* __restrict__ w,
    const float* __restrict__ G0,
    const float* __restrict__ G1,
    const float* __restrict__ M1,
    const float* __restrict__ M2,
    float* __restrict__ out) {
    const int tid = threadIdx.x;
    const int bid = blockIdx.x;
    const int xc = bid & 3;
    const int c  = (bid >> 2) & 31;
    const int bp = bid >> 7;              // [0, NB*NP)
    const int x0 = (xc << 9) + tid;       // column of site 0; site 1 = x0+256
    const float* xb = x + (bp * NT * NC + c) * NX;

    // ---- load both sites' 16-vectors (coalesced) ----
    float X0[16], X1[16];
#pragma unroll
    for (int t = 0; t < 16; ++t) {
        X0[t] = xb[t * NC * NX + x0];
        X1[t] = xb[t * NC * NX + x0 + 256];
    }

    // ---- layer 0: h[e] = sqrt_act( X^T G0[c,e] X ) ----
    float h0[16], h1[16];
    {
        const float* G0c = G0 + c * 4096;
#pragma unroll 1
        for (int e = 0; e < 16; ++e) {
            const float* g = G0c + e * 256;
            float A0 = 0.f, B0 = 0.f, A1 = 0.f, B1 = 0.f;
#pragma unroll
            for (int A = 0; A < 16; ++A) {
                float s0, s1;
                dot2(g + A * 16, X0, X1, s0, s1);
                if (A & 1) { B0 += X0[A] * s0; B1 += X1[A] * s1; }
                else       { A0 += X0[A] * s0; A1 += X1[A] * s1; }
            }
            h0[e] = sqrt_act(A0 + B0);
            h1[e] = sqrt_act(A1 + B1);
        }
    }
    // X0/X1 dead here (re-loaded for the final stage).

    // ---- layer 1: b1[e] = a[e,x] * sqrt_act( h^T G1[e] h ) ----
    float p0[16], p1[16];
    {
#pragma unroll 1
        for (int e = 0; e < 16; ++e) {
            const float* g = G1 + e * 256;
            float A0 = 0.f, B0 = 0.f, A1 = 0.f, B1 = 0.f;
#pragma unroll
            for (int A = 0; A < 16; ++A) {
                float s0, s1;
                dot2(g + A * 16, h0, h1, s0, s1);
                if (A & 1) { B0 += h0[A] * s0; B1 += h1[A] * s1; }
                else       { A0 += h0[A] * s0; A1 += h1[A] * s1; }
            }
            const float ae0 = a[e * NX + x0];
            const float ae1 = a[e * NX + x0 + 256];
            p0[e] = ae0 * sqrt_act(A0 + B0);
            p1[e] = ae1 * sqrt_act(A1 + B1);
        }
    }

    // ---- b2[E] = h^T M1[E] b1  (q1 fused into M1) ----
    float b20[16], b21[16];
    {
#pragma unroll 1
        for (int E = 0; E < 16; ++E) {
            const float* m = M1 + E * 256;
            float A0 = 0.f, B0 = 0.f, A1 = 0.f, B1 = 0.f;
#pragma unroll
            for (int T = 0; T < 16; ++T) {
                float s0, s1;
                dot2(m + T * 16, p0, p1, s0, s1);
                if (T & 1) { B0 += h0[T] * s0; B1 += h1[T] * s1; }
                else       { A0 += h0[T] * s0; A1 += h1[T] * s1; }
            }
            b20[E] = A0 + B0;
            b21[E] = A1 + B1;
        }
    }
    // h, p dead here.

    // ---- re-load X behind an opaque barrier (prevents CSE keeping X alive) ----
    const float* xr = xb;
    asm volatile("" : "+r"(xr));
    float Y0[16], Y1[16];
#pragma unroll
    for (int t = 0; t < 16; ++t) {
        Y0[t] = xr[t * NC * NX + x0];
        Y1[t] = xr[t * NC * NX + x0 + 256];
    }

    // ---- y = sum_T w[T,x] * ( X^T M2[c,T] b2 )  (q0 fused into M2) ----
    float y0 = 0.f, y1 = 0.f;
    {
        const float* M2c = M2 + c * 4096;
#pragma unroll 1
        for (int T = 0; T < 16; ++T) {
            const float* m = M2c + T * 256;
            float A0 = 0.f, B0 = 0.f, A1 = 0.f, B1 = 0.f;
#pragma unroll
            for (int A = 0; A < 16; ++A) {
                float s0, s1;
                dot2(m + A * 16, b20, b21, s0, s1);
                if (A & 1) { B0 += Y0[A] * s0; B1 += Y1[A] * s1; }
                else       { A0 += Y0[A] * s0; A1 += Y1[A] * s1; }
            }
            y0 += w[T * NX + x0]       * (A0 + B0);
            y1 += w[T * NX + x0 + 256] * (A1 + B1);
        }
    }

    // ---- reduce over the block, one atomic per block ----
    float y = y0 + y1;
#pragma unroll
    for (int off = 32; off > 0; off >>= 1) y += __shfl_down(y, off);
    __shared__ float red[4];
    if ((tid & 63) == 0) red[tid >> 6] = y;
    __syncthreads();
    if (tid == 0) {
        atomicAdd(&out[bp * NC + c], red[0] + red[1] + red[2] + red[3]);
    }
}

extern "C" void kernel_launch(void* const* d_in, const int* in_sizes, int n_in,
                              void* d_out, int out_size, void* d_ws, size_t ws_size,
                              hipStream_t stream) {
    const float* x   = (const float*)d_in[0];
    const float* K0  = (const float*)d_in[1];
    const float* Q0  = (const float*)d_in[2];
    const float* V0  = (const float*)d_in[3];
    const float* K1  = (const float*)d_in[4];
    const float* Q1  = (const float*)d_in[5];
    const float* V1  = (const float*)d_in[6];
    const float* enc = (const float*)d_in[7];
    const float* dec = (const float*)d_in[8];
    const float* a   = (const float*)d_in[9];
    const float* w   = (const float*)d_in[10];
    float* out = (float*)d_out;

    float* G0 = (float*)d_ws;        // 32*4096 = 131072 floats
    float* G1 = G0 + NC * 4096;      // 4096
    float* M1 = G1 + 4096;           // 4096
    float* M2 = M1 + 4096;           // 131072
    // total ws: 270336 floats ≈ 1.06 MB

    // out must be zeroed every call (harness re-poisons with 0xAA)
    hipMemsetAsync(d_out, 0, (size_t)out_size * sizeof(float), stream);

    g_precompute<<<NC * 16, 256, 0, stream>>>(K0, V0, enc, G0, NC);
    g_precompute<<<16,      256, 0, stream>>>(K1, V1, enc, G1, 1);
    m1_precompute<<<16,  256, 0, stream>>>(Q1, dec, M1);
    m2_precompute<<<512, 256, 0, stream>>>(Q0, dec, M2);

    const int nblocks = NB * NP * NC * (NX / 512);  // 1024
    site_kernel<<<nblocks, 256, 0, stream>>>(x, a, w, G0, G1, M1, M2, out);
}

// Round 4
// 444.412 us; speedup vs baseline: 8.7640x; 1.2709x over previous
//
#include <hip/hip_runtime.h>
#include <math.h>

// Problem constants (reference: B,P,NTIME,NLATENT,NSPATIAL = 4,2,16,32,2048)
#define NB 4
#define NP 2
#define NT 16
#define NC 32
#define NX 2048

// ---------------------------------------------------------------------------
// Precompute G[c,e,A,B] = sum_{t,T} enc[e,t,T] * K[t,A,c] * V[T,B,c]
// For layer 1 (cstride==1) there is no c axis: G[e,A,B].
// ---------------------------------------------------------------------------
__global__ void g_precompute(const float* __restrict__ K,
                             const float* __restrict__ V,
                             const float* __restrict__ enc,
                             float* __restrict__ G,
                             int cstride) {
    const int bid = blockIdx.x;
    int e, c;
    if (cstride == 1) { e = bid; c = 0; }
    else              { c = bid >> 4; e = bid & 15; }

    __shared__ float sK[256], sV[256], sE[256], sW[256];
    const int tid = threadIdx.x;
    {
        const int t = tid >> 4, A = tid & 15;
        sK[tid] = K[(t * 16 + A) * cstride + c];
        sV[tid] = V[(t * 16 + A) * cstride + c];
        sE[tid] = enc[(e * 16 + t) * 16 + A];
    }
    __syncthreads();
    {   // W[t,B] = sum_T enc[e,t,T] * V[T,B,c]
        const int t = tid >> 4, Bi = tid & 15;
        float acc = 0.f;
#pragma unroll
        for (int T = 0; T < 16; ++T) acc += sE[t * 16 + T] * sV[T * 16 + Bi];
        sW[tid] = acc;
    }
    __syncthreads();
    {   // G[A,B] = sum_t K[t,A,c] * W[t,B]
        const int A = tid >> 4, Bi = tid & 15;
        float acc = 0.f;
#pragma unroll
        for (int t = 0; t < 16; ++t) acc += sK[t * 16 + A] * sW[t * 16 + Bi];
        G[((c * 16 + e) * 16 + A) * 16 + Bi] = acc;
    }
}

// M1[E][T][e] = sum_t Q1[t,T] * dec[e,t,E]   (fuses q1-projection into b2 stage)
__global__ void m1_precompute(const float* __restrict__ Q1,
                              const float* __restrict__ dec,
                              float* __restrict__ M1) {
    const int idx = blockIdx.x * 256 + threadIdx.x;  // 4096
    const int E = idx >> 8, T = (idx >> 4) & 15, e = idx & 15;
    float acc = 0.f;
#pragma unroll
    for (int t = 0; t < 16; ++t)
        acc += Q1[t * 16 + T] * dec[(e * 16 + t) * 16 + E];
    M1[idx] = acc;
}

// M2[c][T][A][E] = sum_t Q0[t,A,c] * dec[E,t,T]  (fuses q0-projection into final stage)
__global__ void m2_precompute(const float* __restrict__ Q0,
                              const float* __restrict__ dec,
                              float* __restrict__ M2) {
    const int idx = blockIdx.x * 256 + threadIdx.x;  // 131072
    const int c = idx >> 12, T = (idx >> 8) & 15, A = (idx >> 4) & 15, E = idx & 15;
    float acc = 0.f;
#pragma unroll
    for (int t = 0; t < 16; ++t)
        acc += Q0[(t * 16 + A) * NC + c] * dec[(E * 16 + t) * 16 + T];
    M2[idx] = acc;
}

__device__ __forceinline__ float sqrt_act(float v) {
    return copysignf(sqrtf(fabsf(v)), v);
}

// dot of one 16-float weight row (LDS-broadcast, in VGPRs after ds_read_b128)
// against TWO per-thread 16-vectors. 4 independent FMA chains.
__device__ __forceinline__ void dot2(const float* __restrict__ row,
                                     const float (&v0)[16], const float (&v1)[16],
                                     float& s0, float& s1) {
    float a0 = 0.f, b0 = 0.f, a1 = 0.f, b1 = 0.f;
#pragma unroll
    for (int i = 0; i < 16; i += 2) {
        a0 += row[i] * v0[i];     b0 += row[i + 1] * v0[i + 1];
        a1 += row[i] * v1[i];     b1 += row[i + 1] * v1[i + 1];
    }
    s0 = a0 + b0;
    s1 = a1 + b1;
}

// ---------------------------------------------------------------------------
// Main kernel: one thread per TWO (b,p,c,x) sites (x and x+256).
// Per-stage weight matrices (16 KB each) are staged into LDS; inner loops
// read weight rows via wave-uniform ds_read_b128 (broadcast, conflict-free,
// ~120 cyc latency the compiler pipelines) instead of serialized s_loads.
// grid = NB*NP*NC*(NX/512) = 1024 blocks of 256 threads = 4 blocks/CU.
// ---------------------------------------------------------------------------
__global__ __launch_bounds__(256) void site_kernel(
    const float* __restrict__ x,
    const float* __restrict__ a,
    const float* __restrict__ w,
    const float* __restrict__ G0,
    const float* __restrict__ G1,
    const float* __restrict__ M1,
    const float* __restrict__ M2,
    float* __restrict__ out) {
    const int tid = threadIdx.x;
    const int bid = blockIdx.x;
    const int xc = bid & 3;
    const int c  = (bid >> 2) & 31;
    const int bp = bid >> 7;              // [0, NB*NP)
    const int x0 = (xc << 9) + tid;       // column of site 0; site 1 = x0+256
    const float* xb = x + (bp * NT * NC + c) * NX;

    __shared__ float sw[4096];            // one stage's 16 KB weight matrix

    // cooperative 16 KB fill: 256 threads x 4 float4
#define FILL(SRC)                                                         \
    do {                                                                  \
        const float4* s4 = (const float4*)(SRC);                          \
        float4* d4 = (float4*)sw;                                         \
        _Pragma("unroll")                                                 \
        for (int i = 0; i < 4; ++i) d4[tid + 256 * i] = s4[tid + 256 * i];\
    } while (0)

    // ---- load both sites' 16-vectors (coalesced) ----
    float X0[16], X1[16];
#pragma unroll
    for (int t = 0; t < 16; ++t) {
        X0[t] = xb[t * NC * NX + x0];
        X1[t] = xb[t * NC * NX + x0 + 256];
    }

    // ======== layer 0: h[e] = sqrt_act( X^T G0[c,e] X ) ========
    FILL(G0 + c * 4096);
    __syncthreads();
    float h0[16], h1[16];
    {
#pragma unroll 1
        for (int e = 0; e < 16; ++e) {
            const float* g = sw + e * 256;
            float A0 = 0.f, B0 = 0.f, A1 = 0.f, B1 = 0.f;
#pragma unroll
            for (int A = 0; A < 16; ++A) {
                float s0, s1;
                dot2(g + A * 16, X0, X1, s0, s1);
                if (A & 1) { B0 += X0[A] * s0; B1 += X1[A] * s1; }
                else       { A0 += X0[A] * s0; A1 += X1[A] * s1; }
            }
            h0[e] = sqrt_act(A0 + B0);
            h1[e] = sqrt_act(A1 + B1);
        }
    }
    // X0/X1 dead here (re-loaded for the final stage).

    // ======== layer 1: b1[e] = a[e,x] * sqrt_act( h^T G1[e] h ) ========
    __syncthreads();
    FILL(G1);
    __syncthreads();
    float p0[16], p1[16];
    {
#pragma unroll 1
        for (int e = 0; e < 16; ++e) {
            const float* g = sw + e * 256;
            float A0 = 0.f, B0 = 0.f, A1 = 0.f, B1 = 0.f;
#pragma unroll
            for (int A = 0; A < 16; ++A) {
                float s0, s1;
                dot2(g + A * 16, h0, h1, s0, s1);
                if (A & 1) { B0 += h0[A] * s0; B1 += h1[A] * s1; }
                else       { A0 += h0[A] * s0; A1 += h1[A] * s1; }
            }
            const float ae0 = a[e * NX + x0];
            const float ae1 = a[e * NX + x0 + 256];
            p0[e] = ae0 * sqrt_act(A0 + B0);
            p1[e] = ae1 * sqrt_act(A1 + B1);
        }
    }

    // ======== b2[E] = h^T M1[E] b1  (q1 fused into M1) ========
    __syncthreads();
    FILL(M1);
    __syncthreads();
    float b20[16], b21[16];
    {
#pragma unroll 1
        for (int E = 0; E < 16; ++E) {
            const float* m = sw + E * 256;
            float A0 = 0.f, B0 = 0.f, A1 = 0.f, B1 = 0.f;
#pragma unroll
            for (int T = 0; T < 16; ++T) {
                float s0, s1;
                dot2(m + T * 16, p0, p1, s0, s1);
                if (T & 1) { B0 += h0[T] * s0; B1 += h1[T] * s1; }
                else       { A0 += h0[T] * s0; A1 += h1[T] * s1; }
            }
            b20[E] = A0 + B0;
            b21[E] = A1 + B1;
        }
    }
    // h, p dead here.

    // ---- re-load X behind an opaque barrier (prevents CSE keeping X alive) ----
    const float* xr = xb;
    asm volatile("" : "+r"(xr));
    float Y0[16], Y1[16];
#pragma unroll
    for (int t = 0; t < 16; ++t) {
        Y0[t] = xr[t * NC * NX + x0];
        Y1[t] = xr[t * NC * NX + x0 + 256];
    }

    // ======== y = sum_T w[T,x] * ( X^T M2[c,T] b2 )  (q0 fused into M2) ========
    __syncthreads();
    FILL(M2 + c * 4096);
    __syncthreads();
    float y0 = 0.f, y1 = 0.f;
    {
#pragma unroll 1
        for (int T = 0; T < 16; ++T) {
            const float* m = sw + T * 256;
            float A0 = 0.f, B0 = 0.f, A1 = 0.f, B1 = 0.f;
#pragma unroll
            for (int A = 0; A < 16; ++A) {
                float s0, s1;
                dot2(m + A * 16, b20, b21, s0, s1);
                if (A & 1) { B0 += Y0[A] * s0; B1 += Y1[A] * s1; }
                else       { A0 += Y0[A] * s0; A1 += Y1[A] * s1; }
            }
            y0 += w[T * NX + x0]       * (A0 + B0);
            y1 += w[T * NX + x0 + 256] * (A1 + B1);
        }
    }
#undef FILL

    // ---- reduce over the block, one atomic per block ----
    float y = y0 + y1;
#pragma unroll
    for (int off = 32; off > 0; off >>= 1) y += __shfl_down(y, off);
    __shared__ float red[4];
    if ((tid & 63) == 0) red[tid >> 6] = y;
    __syncthreads();
    if (tid == 0) {
        atomicAdd(&out[bp * NC + c], red[0] + red[1] + red[2] + red[3]);
    }
}

extern "C" void kernel_launch(void* const* d_in, const int* in_sizes, int n_in,
                              void* d_out, int out_size, void* d_ws, size_t ws_size,
                              hipStream_t stream) {
    const float* x   = (const float*)d_in[0];
    const float* K0  = (const float*)d_in[1];
    const float* Q0  = (const float*)d_in[2];
    const float* V0  = (const float*)d_in[3];
    const float* K1  = (const float*)d_in[4];
    const float* Q1  = (const float*)d_in[5];
    const float* V1  = (const float*)d_in[6];
    const float* enc = (const float*)d_in[7];
    const float* dec = (const float*)d_in[8];
    const float* a   = (const float*)d_in[9];
    const float* w   = (const float*)d_in[10];
    float* out = (float*)d_out;

    float* G0 = (float*)d_ws;        // 32*4096 = 131072 floats
    float* G1 = G0 + NC * 4096;      // 4096
    float* M1 = G1 + 4096;           // 4096
    float* M2 = M1 + 4096;           // 131072
    // total ws: 270336 floats ~= 1.06 MB

    // out must be zeroed every call (harness re-poisons with 0xAA)
    hipMemsetAsync(d_out, 0, (size_t)out_size * sizeof(float), stream);

    g_precompute<<<NC * 16, 256, 0, stream>>>(K0, V0, enc, G0, NC);
    g_precompute<<<16,      256, 0, stream>>>(K1, V1, enc, G1, 1);
    m1_precompute<<<16,  256, 0, stream>>>(Q1, dec, M1);
    m2_precompute<<<512, 256, 0, stream>>>(Q0, dec, M2);

    const int nblocks = NB * NP * NC * (NX / 512);  // 1024
    site_kernel<<<nblocks, 256, 0, stream>>>(x, a, w, G0, G1, M1, M2, out);
}